// Round 1
// baseline (515.537 us; speedup 1.0000x reference)
//
#include <hip/hip_runtime.h>
#include <math.h>

#define BB 256
#define KK 2
#define EE 16
#define DD 512
#define BK (BB*KK)   // 512

// ws layout (ints/floats over the same buffer):
//   int  wcnt[16]            @ int offset 0
//   int  bcnt[16]            @ int offset 16
//   int  wlist[EE*BK]        @ int offset 1024   (byte 4096, 32KB)
//   int  blist[EE*BK]        @ int offset 10240  (byte 40960, 32KB)
//   f32  iv[BK*DD]           @ f32 offset 20480  (byte 81920, 1MB)
//   f32  ov[BK*DD]           @ +262144
//   f32  dv[BK*DD]           @ +524288
//   f32  bv[BK*DD]           @ +786432
#define WS_F_BASE 20480
#define SLAB (BK*DD)

// ---------------------------------------------------------------- kernel A
__global__ void build_lists(const int* __restrict__ widx,
                            const int* __restrict__ bidx,
                            int* __restrict__ ws) {
    int* wcnt  = ws;
    int* bcnt  = ws + 16;
    int* wlist = ws + 1024;
    int* blist = ws + 10240;
    int t = threadIdx.x;            // 0..511
    if (t < 16) { wcnt[t] = 0; bcnt[t] = 0; }
    __syncthreads();
    int e  = widx[t];
    int p  = atomicAdd(&wcnt[e], 1);
    wlist[e * BK + p] = t;
    int eb = bidx[t];
    int pb = atomicAdd(&bcnt[eb], 1);
    blist[eb * BK + pb] = t;
}

// ---------------------------------------------------------------- kernel B
// grid (64 row-chunks, 16 experts, 4 banks), block 256.
// Each block: expert e, bank z, up to 8 (b,k) rows; streams the 1MB slab once,
// x rows staged in LDS, acc in registers. out[p*D + j].
__launch_bounds__(256)
__global__ void expert_vm(const float* __restrict__ x,
                          const float* __restrict__ w_in,
                          const float* __restrict__ w_out,
                          const float* __restrict__ w_diag,
                          const float* __restrict__ w_bias,
                          int* __restrict__ ws_i,
                          float* __restrict__ ws_f) {
    const int z = blockIdx.z;
    const int e = blockIdx.y;
    const int* cnt  = (z < 3) ? ws_i        : ws_i + 16;
    const int* list = (z < 3) ? ws_i + 1024 : ws_i + 10240;
    const int n  = cnt[e];
    const int r0 = blockIdx.x * 8;
    if (r0 >= n) return;
    const int rows = min(8, n - r0);

    const float* W = (z == 0 ? w_in : z == 1 ? w_out : z == 2 ? w_diag : w_bias)
                     + (size_t)e * DD * DD;
    float* out = ws_f + WS_F_BASE + (size_t)z * SLAB;

    __shared__ int    plist[8];
    __shared__ float4 xs4[8 * 128];       // 8 rows x 512 f32 = 16KB
    const int t = threadIdx.x;
    if (t < 8) plist[t] = (t < rows) ? list[e * BK + r0 + t] : -1;
    __syncthreads();
    const float4* x4 = (const float4*)x;
    #pragma unroll
    for (int q = 0; q < 4; ++q) {
        int f = t + q * 256;              // 0..1023
        int r = f >> 7, c = f & 127;
        int p = plist[r];
        xs4[f] = (p >= 0) ? x4[(p >> 1) * 128 + c] : make_float4(0.f, 0.f, 0.f, 0.f);
    }
    __syncthreads();

    float acc0[8], acc1[8];
    #pragma unroll
    for (int r = 0; r < 8; ++r) { acc0[r] = 0.f; acc1[r] = 0.f; }
    const int j0 = t, j1 = t + 256;

    for (int i4 = 0; i4 < 128; ++i4) {
        float w0[4], w1[4];
        #pragma unroll
        for (int q = 0; q < 4; ++q) {
            w0[q] = W[(i4 * 4 + q) * DD + j0];
            w1[q] = W[(i4 * 4 + q) * DD + j1];
        }
        #pragma unroll
        for (int r = 0; r < 8; ++r) {
            float4 xv = xs4[r * 128 + i4];   // broadcast b128 read
            acc0[r] += xv.x * w0[0]; acc1[r] += xv.x * w1[0];
            acc0[r] += xv.y * w0[1]; acc1[r] += xv.y * w1[1];
            acc0[r] += xv.z * w0[2]; acc1[r] += xv.z * w1[2];
            acc0[r] += xv.w * w0[3]; acc1[r] += xv.w * w1[3];
        }
    }
    for (int r = 0; r < rows; ++r) {
        int p = plist[r];
        out[(size_t)p * DD + j0] = acc0[r];
        out[(size_t)p * DD + j1] = acc1[r];
    }
}

// ---------------------------------------------------------------- kernel C
// grid (8 row-chunks, 256 batch), block 256. Closed-form LayerNorm of the
// rank-2+diag mixture; writes 64 rows x 512 f32 per block (float2 stores).
__launch_bounds__(256)
__global__ void gen_write(const float* __restrict__ ws_f,
                          const float* __restrict__ wp,
                          float* __restrict__ outp) {
    const int b     = blockIdx.y;
    const int chunk = blockIdx.x;      // 64-row chunk
    const float* iv = ws_f + WS_F_BASE;
    const float* ov = iv + SLAB;
    const float* dv = ov + SLAB;

    __shared__ float ov1[DD], ov2[DD];
    __shared__ float S[5];
    __shared__ float red[4 * 5];
    __shared__ float sa1[64], sa2[64], sdd[64], smu[64], srs[64];
    const int t = threadIdx.x;

    const float* ovp0 = ov + (size_t)(b * 2 + 0) * DD;
    const float* ovp1 = ov + (size_t)(b * 2 + 1) * DD;
    ov1[t] = ovp0[t]; ov1[t + 256] = ovp0[t + 256];
    ov2[t] = ovp1[t]; ov2[t + 256] = ovp1[t + 256];
    __syncthreads();

    float v0a = ov1[t], v0b = ov1[t + 256], v1a = ov2[t], v1b = ov2[t + 256];
    float s[5];
    s[0] = v0a + v0b;
    s[1] = v1a + v1b;
    s[2] = v0a * v0a + v0b * v0b;
    s[3] = v0a * v1a + v0b * v1b;
    s[4] = v1a * v1a + v1b * v1b;
    #pragma unroll
    for (int off = 32; off; off >>= 1) {
        #pragma unroll
        for (int q = 0; q < 5; ++q) s[q] += __shfl_down(s[q], off);
    }
    const int lane = t & 63, wv = t >> 6;
    if (lane == 0) {
        #pragma unroll
        for (int q = 0; q < 5; ++q) red[wv * 5 + q] = s[q];
    }
    __syncthreads();
    if (t == 0) {
        #pragma unroll
        for (int q = 0; q < 5; ++q) S[q] = red[q] + red[5 + q] + red[10 + q] + red[15 + q];
    }
    __syncthreads();

    if (t < 64) {
        const float S1 = S[0], S2 = S[1], S11 = S[2], S12 = S[3], S22 = S[4];
        int i = chunk * 64 + t;
        float wp0 = wp[b * 2], wp1 = wp[b * 2 + 1];
        float a1 = wp0 * iv[(size_t)(b * 2 + 0) * DD + i];
        float a2 = wp1 * iv[(size_t)(b * 2 + 1) * DD + i];
        float dd = wp0 * dv[(size_t)(b * 2 + 0) * DD + i]
                 + wp1 * dv[(size_t)(b * 2 + 1) * DD + i];
        float mu = (a1 * S1 + a2 * S2 + dd) * (1.0f / DD);
        float e2 = (a1 * a1 * S11 + 2.0f * a1 * a2 * S12 + a2 * a2 * S22
                    + 2.0f * (a1 * ov1[i] + a2 * ov2[i]) * dd + dd * dd) * (1.0f / DD);
        float var = e2 - mu * mu;
        sa1[t] = a1; sa2[t] = a2; sdd[t] = dd; smu[t] = mu;
        srs[t] = rsqrtf(var + 1e-5f);
    }
    __syncthreads();

    const int o = 2 * t;
    float2* outv = (float2*)(outp + ((size_t)b * DD + chunk * 64) * DD);
    #pragma unroll 2
    for (int r = 0; r < 64; ++r) {
        int i = chunk * 64 + r;
        float a1 = sa1[r], a2 = sa2[r], dd = sdd[r], mu = smu[r], rs = srs[r];
        float w0 = a1 * ov1[o]     + a2 * ov2[o];
        float w1 = a1 * ov1[o + 1] + a2 * ov2[o + 1];
        if (o     == i) w0 += dd;
        if (o + 1 == i) w1 += dd;
        outv[r * (DD / 2) + t] = make_float2((w0 - mu) * rs, (w1 - mu) * rs);
    }
}

// ---------------------------------------------------------------- kernel D
__global__ void bias_mix(const float* __restrict__ ws_f,
                         const float* __restrict__ bp,
                         float* __restrict__ outp) {
    const float* bv = ws_f + WS_F_BASE + 3 * (size_t)SLAB;
    int b = blockIdx.x;
    int t = threadIdx.x;
    float p0 = bp[b * 2], p1 = bp[b * 2 + 1];
    const float* b0 = bv + (size_t)(b * 2 + 0) * DD;
    const float* b1 = bv + (size_t)(b * 2 + 1) * DD;
    outp[(size_t)b * DD + t]       = p0 * b0[t]       + p1 * b1[t];
    outp[(size_t)b * DD + t + 256] = p0 * b0[t + 256] + p1 * b1[t + 256];
}

// ---------------------------------------------------------------- launch
extern "C" void kernel_launch(void* const* d_in, const int* in_sizes, int n_in,
                              void* d_out, int out_size, void* d_ws, size_t ws_size,
                              hipStream_t stream) {
    const float* x      = (const float*)d_in[0];
    const float* wprobs = (const float*)d_in[1];
    const float* bprobs = (const float*)d_in[2];
    const float* w_in   = (const float*)d_in[3];
    const float* w_out  = (const float*)d_in[4];
    const float* w_diag = (const float*)d_in[5];
    const float* w_bias = (const float*)d_in[6];
    const int*   widx   = (const int*)d_in[7];
    const int*   bidx   = (const int*)d_in[8];
    float* out  = (float*)d_out;
    int*   wsI  = (int*)d_ws;
    float* wsF  = (float*)d_ws;

    build_lists<<<1, BK, 0, stream>>>(widx, bidx, wsI);

    expert_vm<<<dim3(64, EE, 4), 256, 0, stream>>>(x, w_in, w_out, w_diag, w_bias,
                                                   wsI, wsF);

    gen_write<<<dim3(8, BB), 256, 0, stream>>>(wsF, wprobs, out);

    bias_mix<<<BB, 256, 0, stream>>>(wsF, bprobs, out + (size_t)BB * DD * DD);
}

// Round 3
// 414.491 us; speedup vs baseline: 1.2438x; 1.2438x over previous
//
#include <hip/hip_runtime.h>
#include <math.h>

#define BB 256
#define KK 2
#define EE 16
#define DD 512
#define BK (BB*KK)   // 512

// ws layout (ints/floats over same buffer):
//   int  wlist[EE*BK]   @ int 1024
//   int  blist[EE*BK]   @ int 10240
//   int  wchunks        @ int 18432  ([0]=count, [1..] = e | r0<<8 | rows<<20)
//   int  bchunks        @ int 18560
//   f32  iv/ov/dv/bv slabs @ f32 20480, each BK*DD
#define WCH 18432
#define BCH 18560
#define WS_F_BASE 20480
#define SLAB (BK*DD)

// ---------------------------------------------------------------- kernel A
__global__ void build_lists(const int* __restrict__ widx,
                            const int* __restrict__ bidx,
                            int* __restrict__ ws) {
    __shared__ int scw[16], scb[16];
    int* wlist = ws + 1024;
    int* blist = ws + 10240;
    const int t = threadIdx.x;        // 0..511
    if (t < 16) { scw[t] = 0; scb[t] = 0; }
    __syncthreads();
    int e = widx[t];
    int p = atomicAdd(&scw[e], 1);
    wlist[e * BK + p] = t;
    int eb = bidx[t];
    int pb = atomicAdd(&scb[eb], 1);
    blist[eb * BK + pb] = t;
    __syncthreads();
    if (t == 0) {
        int nc = 0;
        for (int e2 = 0; e2 < 16; ++e2) {
            int n = scw[e2];
            for (int r = 0; r < n; r += 16)
                ws[WCH + 1 + nc++] = e2 | (r << 8) | (min(16, n - r) << 20);
        }
        ws[WCH] = nc;
    }
    if (t == 64) {
        int nc = 0;
        for (int e2 = 0; e2 < 16; ++e2) {
            int n = scb[e2];
            for (int r = 0; r < n; r += 16)
                ws[BCH + 1 + nc++] = e2 | (r << 8) | (min(16, n - r) << 20);
        }
        ws[BCH] = nc;
    }
}

// ---------------------------------------------------------------- kernel B
// grid (4 colchunks, 48 chunk slots, 4 banks), block 256.
// Chunk = expert e, up to 16 (b,k) rows. Thread: 1 col x 8 rows, acc[8].
// x rows staged in LDS as float4-across-rows -> 2 broadcast b128 reads per i.
__launch_bounds__(256)
__global__ void expert_vm(const float* __restrict__ x,
                          const float* __restrict__ w_in,
                          const float* __restrict__ w_out,
                          const float* __restrict__ w_diag,
                          const float* __restrict__ w_bias,
                          const int* __restrict__ ws_i,
                          float* __restrict__ ws_f) {
    const int z = blockIdx.z;
    const int* ch = ws_i + ((z < 3) ? WCH : BCH);
    const int slot = blockIdx.y;
    if (slot >= ch[0]) return;
    const int desc = ch[1 + slot];
    const int e = desc & 0xff, r0 = (desc >> 8) & 0xfff, rows = desc >> 20;
    const int* list = ws_i + ((z < 3) ? 1024 : 10240) + e * BK + r0;
    const float* W = (z == 0 ? w_in : z == 1 ? w_out : z == 2 ? w_diag : w_bias)
                     + (size_t)e * DD * DD;
    float* out = ws_f + WS_F_BASE + (size_t)z * SLAB;

    __shared__ int plist[16];
    __shared__ float4 xs[DD][4];      // [i][q]: rows 4q..4q+3 at col i (32KB)
    const int t = threadIdx.x;
    if (t < 16) plist[t] = (t < rows) ? list[t] : -1;
    __syncthreads();
    #pragma unroll
    for (int k = 0; k < 8; ++k) {
        int idx = t + k * 256;        // 0..2047
        int i = idx >> 2, q = idx & 3;
        int p0 = plist[q * 4 + 0], p1 = plist[q * 4 + 1];
        int p2 = plist[q * 4 + 2], p3 = plist[q * 4 + 3];
        float4 v;
        // NOTE: plist entries are (b,k) flat indices 0..511; x is [B][D] so
        // the batch row is p >> 1.  (R2 bug: missing >>1 read OOB for b>=128.)
        v.x = (p0 >= 0) ? x[(p0 >> 1) * DD + i] : 0.f;
        v.y = (p1 >= 0) ? x[(p1 >> 1) * DD + i] : 0.f;
        v.z = (p2 >= 0) ? x[(p2 >> 1) * DD + i] : 0.f;
        v.w = (p3 >= 0) ? x[(p3 >> 1) * DD + i] : 0.f;
        xs[i][q] = v;
    }
    __syncthreads();

    const int col = blockIdx.x * 128 + (t & 127);
    const int h = t >> 7;             // 0: rows 0-7, 1: rows 8-15
    const float* Wc = W + col;
    float a0 = 0, a1 = 0, a2 = 0, a3 = 0, b0 = 0, b1 = 0, b2 = 0, b3 = 0;
    #pragma unroll 8
    for (int i = 0; i < DD; ++i) {
        float w = Wc[(size_t)i * DD];       // coalesced 4B/lane
        float4 xa = xs[i][2 * h];           // broadcast b128
        float4 xb = xs[i][2 * h + 1];       // broadcast b128
        a0 += xa.x * w; a1 += xa.y * w; a2 += xa.z * w; a3 += xa.w * w;
        b0 += xb.x * w; b1 += xb.y * w; b2 += xb.z * w; b3 += xb.w * w;
    }
    float accs[8] = {a0, a1, a2, a3, b0, b1, b2, b3};
    #pragma unroll
    for (int r = 0; r < 8; ++r) {
        int p = plist[h * 8 + r];
        if (p >= 0) out[(size_t)p * DD + col] = accs[r];
    }
}

// ---------------------------------------------------------------- kernel C
// grid (8 chunks, 256 batch), block 256. Closed-form LayerNorm of the
// rank-2+diag mixture; float4 stores (16B/lane), 32 iters of 2 rows.
__launch_bounds__(256)
__global__ void gen_write(const float* __restrict__ ws_f,
                          const float* __restrict__ wp,
                          float* __restrict__ outp) {
    const int b = blockIdx.y;
    const int chunk = blockIdx.x;         // 64-row chunk
    const float* iv  = ws_f + WS_F_BASE;
    const float* ovs = iv + SLAB;
    const float* dvs = ovs + SLAB;

    __shared__ float4 ov1v[128], ov2v[128];
    __shared__ float S[5], red[20];
    __shared__ float sa1[64], sa2[64], sdd[64], smu[64], srs[64];
    const int t = threadIdx.x;
    const float* ov1 = (const float*)ov1v;
    const float* ov2 = (const float*)ov2v;

    const float4* ovp0 = (const float4*)(ovs + (size_t)(b * 2 + 0) * DD);
    const float4* ovp1 = (const float4*)(ovs + (size_t)(b * 2 + 1) * DD);
    if (t < 128) ov1v[t] = ovp0[t];
    else         ov2v[t - 128] = ovp1[t - 128];
    __syncthreads();

    float v0a = ov1[t], v0b = ov1[t + 256], v1a = ov2[t], v1b = ov2[t + 256];
    float s[5];
    s[0] = v0a + v0b;
    s[1] = v1a + v1b;
    s[2] = v0a * v0a + v0b * v0b;
    s[3] = v0a * v1a + v0b * v1b;
    s[4] = v1a * v1a + v1b * v1b;
    #pragma unroll
    for (int off = 32; off; off >>= 1) {
        #pragma unroll
        for (int q = 0; q < 5; ++q) s[q] += __shfl_down(s[q], off);
    }
    const int lane = t & 63, wv = t >> 6;
    if (lane == 0) {
        #pragma unroll
        for (int q = 0; q < 5; ++q) red[wv * 5 + q] = s[q];
    }
    __syncthreads();
    if (t == 0) {
        #pragma unroll
        for (int q = 0; q < 5; ++q) S[q] = red[q] + red[5 + q] + red[10 + q] + red[15 + q];
    }
    __syncthreads();

    if (t < 64) {
        const float S1 = S[0], S2 = S[1], S11 = S[2], S12 = S[3], S22 = S[4];
        int i = chunk * 64 + t;
        float wp0 = wp[b * 2], wp1 = wp[b * 2 + 1];
        float a1 = wp0 * iv[(size_t)(b * 2 + 0) * DD + i];
        float a2 = wp1 * iv[(size_t)(b * 2 + 1) * DD + i];
        float dd = wp0 * dvs[(size_t)(b * 2 + 0) * DD + i]
                 + wp1 * dvs[(size_t)(b * 2 + 1) * DD + i];
        float mu = (a1 * S1 + a2 * S2 + dd) * (1.0f / DD);
        float e2 = (a1 * a1 * S11 + 2.0f * a1 * a2 * S12 + a2 * a2 * S22
                    + 2.0f * (a1 * ov1[i] + a2 * ov2[i]) * dd + dd * dd) * (1.0f / DD);
        float var = e2 - mu * mu;
        sa1[t] = a1; sa2[t] = a2; sdd[t] = dd; smu[t] = mu;
        srs[t] = rsqrtf(var + 1e-5f);
    }
    __syncthreads();

    const int ci = t & 127, rh = t >> 7;
    const float4 o1 = ov1v[ci], o2 = ov2v[ci];   // loop-invariant, hoisted
    const int jj = ci * 4;
    float* obase = outp + ((size_t)b * DD + chunk * 64) * DD;
    #pragma unroll 2
    for (int rr = 0; rr < 32; ++rr) {
        int r = rr * 2 + rh;
        int irow = chunk * 64 + r;
        float a1 = sa1[r], a2 = sa2[r], dd = sdd[r], mu = smu[r], rs = srs[r];
        float4 w;
        w.x = a1 * o1.x + a2 * o2.x + ((irow == jj)     ? dd : 0.f);
        w.y = a1 * o1.y + a2 * o2.y + ((irow == jj + 1) ? dd : 0.f);
        w.z = a1 * o1.z + a2 * o2.z + ((irow == jj + 2) ? dd : 0.f);
        w.w = a1 * o1.w + a2 * o2.w + ((irow == jj + 3) ? dd : 0.f);
        w.x = (w.x - mu) * rs; w.y = (w.y - mu) * rs;
        w.z = (w.z - mu) * rs; w.w = (w.w - mu) * rs;
        ((float4*)(obase + (size_t)r * DD))[ci] = w;
    }
}

// ---------------------------------------------------------------- kernel D
__global__ void bias_mix(const float* __restrict__ ws_f,
                         const float* __restrict__ bp,
                         float* __restrict__ outp) {
    const float* bv = ws_f + WS_F_BASE + 3 * (size_t)SLAB;
    int b = blockIdx.x;
    int t = threadIdx.x;
    float p0 = bp[b * 2], p1 = bp[b * 2 + 1];
    const float* b0 = bv + (size_t)(b * 2 + 0) * DD;
    const float* b1 = bv + (size_t)(b * 2 + 1) * DD;
    outp[(size_t)b * DD + t]       = p0 * b0[t]       + p1 * b1[t];
    outp[(size_t)b * DD + t + 256] = p0 * b0[t + 256] + p1 * b1[t + 256];
}

// ---------------------------------------------------------------- launch
extern "C" void kernel_launch(void* const* d_in, const int* in_sizes, int n_in,
                              void* d_out, int out_size, void* d_ws, size_t ws_size,
                              hipStream_t stream) {
    const float* x      = (const float*)d_in[0];
    const float* wprobs = (const float*)d_in[1];
    const float* bprobs = (const float*)d_in[2];
    const float* w_in   = (const float*)d_in[3];
    const float* w_out  = (const float*)d_in[4];
    const float* w_diag = (const float*)d_in[5];
    const float* w_bias = (const float*)d_in[6];
    const int*   widx   = (const int*)d_in[7];
    const int*   bidx   = (const int*)d_in[8];
    float* out = (float*)d_out;
    int*   wsI = (int*)d_ws;
    float* wsF = (float*)d_ws;

    build_lists<<<1, BK, 0, stream>>>(widx, bidx, wsI);

    expert_vm<<<dim3(4, 48, 4), 256, 0, stream>>>(x, w_in, w_out, w_diag, w_bias,
                                                  wsI, wsF);

    gen_write<<<dim3(8, BB), 256, 0, stream>>>(wsF, wprobs, out);

    bias_mix<<<BB, 256, 0, stream>>>(wsF, bprobs, out + (size_t)BB * DD * DD);
}

// Round 4
// 396.500 us; speedup vs baseline: 1.3002x; 1.0454x over previous
//
#include <hip/hip_runtime.h>
#include <math.h>

#define BB 256
#define KK 2
#define EE 16
#define DD 512
#define BK (BB*KK)   // 512
#define NP 4         // K-dim partials (i-split)

// ws layout (ints/floats over same buffer):
//   int  wlist[EE*BK]   @ int 1024
//   int  blist[EE*BK]   @ int 10240
//   int  wchunks        @ int 18432  ([0]=count, [1..] = e | r0<<8 | rows<<20)
//   int  bchunks        @ int 18560
//   f32  16 partial slabs @ f32 20480: slab(z,p) = (z*NP+p)*SLAB, each BK*DD
//        z: 0=iv 1=ov 2=dv 3=bv; p: i-range [p*128,(p+1)*128)
#define WCH 18432
#define BCH 18560
#define WS_F_BASE 20480
#define SLAB (BK*DD)

// ---------------------------------------------------------------- kernel A
__global__ void build_lists(const int* __restrict__ widx,
                            const int* __restrict__ bidx,
                            int* __restrict__ ws) {
    __shared__ int scw[16], scb[16];
    int* wlist = ws + 1024;
    int* blist = ws + 10240;
    const int t = threadIdx.x;        // 0..511
    if (t < 16) { scw[t] = 0; scb[t] = 0; }
    __syncthreads();
    int e = widx[t];
    int p = atomicAdd(&scw[e], 1);
    wlist[e * BK + p] = t;
    int eb = bidx[t];
    int pb = atomicAdd(&scb[eb], 1);
    blist[eb * BK + pb] = t;
    __syncthreads();
    if (t == 0) {
        int nc = 0;
        for (int e2 = 0; e2 < 16; ++e2) {
            int n = scw[e2];
            for (int r = 0; r < n; r += 16)
                ws[WCH + 1 + nc++] = e2 | (r << 8) | (min(16, n - r) << 20);
        }
        ws[WCH] = nc;
    }
    if (t == 64) {
        int nc = 0;
        for (int e2 = 0; e2 < 16; ++e2) {
            int n = scb[e2];
            for (int r = 0; r < n; r += 16)
                ws[BCH + 1 + nc++] = e2 | (r << 8) | (min(16, n - r) << 20);
        }
        ws[BCH] = nc;
    }
}

// ---------------------------------------------------------------- kernel B
// grid (4 colchunks, 48 chunk slots, 16 z*p), block 256.
// Chunk = expert e, up to 16 (b,k) rows; this block does K-partial
// i in [p*128,(p+1)*128) for 128 cols. Thread: 1 col x 8 rows, acc[8].
__launch_bounds__(256)
__global__ void expert_vm(const float* __restrict__ x,
                          const float* __restrict__ w_in,
                          const float* __restrict__ w_out,
                          const float* __restrict__ w_diag,
                          const float* __restrict__ w_bias,
                          const int* __restrict__ ws_i,
                          float* __restrict__ ws_f) {
    const int zp = blockIdx.z;                 // 0..15
    const int z = zp >> 2, ip = zp & 3;
    const int* ch = ws_i + ((z < 3) ? WCH : BCH);
    const int slot = blockIdx.y;
    if (slot >= ch[0]) return;
    const int desc = ch[1 + slot];
    const int e = desc & 0xff, r0 = (desc >> 8) & 0xfff, rows = desc >> 20;
    const int* list = ws_i + ((z < 3) ? 1024 : 10240) + e * BK + r0;
    const int i0 = ip * 128;
    const float* W = (z == 0 ? w_in : z == 1 ? w_out : z == 2 ? w_diag : w_bias)
                     + (size_t)e * DD * DD + (size_t)i0 * DD;
    float* out = ws_f + WS_F_BASE + (size_t)zp * SLAB;

    __shared__ int plist[16];
    __shared__ float4 xs[128][4];      // [i_local][q]: rows 4q..4q+3 (8KB)
    const int t = threadIdx.x;
    if (t < 16) plist[t] = (t < rows) ? list[t] : -1;
    __syncthreads();
    #pragma unroll
    for (int k = 0; k < 2; ++k) {
        int idx = t + k * 256;         // 0..511
        int i = idx >> 2, q = idx & 3;
        int p0 = plist[q * 4 + 0], p1 = plist[q * 4 + 1];
        int p2 = plist[q * 4 + 2], p3 = plist[q * 4 + 3];
        float4 v;
        // plist entries are (b,k) flat 0..511; x row is p>>1.
        v.x = (p0 >= 0) ? x[(p0 >> 1) * DD + i0 + i] : 0.f;
        v.y = (p1 >= 0) ? x[(p1 >> 1) * DD + i0 + i] : 0.f;
        v.z = (p2 >= 0) ? x[(p2 >> 1) * DD + i0 + i] : 0.f;
        v.w = (p3 >= 0) ? x[(p3 >> 1) * DD + i0 + i] : 0.f;
        xs[i][q] = v;
    }
    __syncthreads();

    const int col = blockIdx.x * 128 + (t & 127);
    const int h = t >> 7;              // 0: rows 0-7, 1: rows 8-15
    const float* Wc = W + col;
    float a0 = 0, a1 = 0, a2 = 0, a3 = 0, b0 = 0, b1 = 0, b2 = 0, b3 = 0;
    #pragma unroll 16
    for (int i = 0; i < 128; ++i) {
        float w = Wc[(size_t)i * DD];        // coalesced 4B/lane
        float4 xa = xs[i][2 * h];            // broadcast b128
        float4 xb = xs[i][2 * h + 1];        // broadcast b128
        a0 += xa.x * w; a1 += xa.y * w; a2 += xa.z * w; a3 += xa.w * w;
        b0 += xb.x * w; b1 += xb.y * w; b2 += xb.z * w; b3 += xb.w * w;
    }
    float accs[8] = {a0, a1, a2, a3, b0, b1, b2, b3};
    #pragma unroll
    for (int r = 0; r < 8; ++r) {
        int p = plist[h * 8 + r];
        if (p >= 0) out[(size_t)p * DD + col] = accs[r];
    }
}

// ---------------------------------------------------------------- kernel C
// grid (8 chunks, 256 batch), block 256. Closed-form LayerNorm of the
// rank-2+diag mixture; sums the NP K-partials at load time.
__launch_bounds__(256)
__global__ void gen_write(const float* __restrict__ ws_f,
                          const float* __restrict__ wp,
                          float* __restrict__ outp) {
    const int b = blockIdx.y;
    const int chunk = blockIdx.x;          // 64-row chunk
    const float* base = ws_f + WS_F_BASE;

    __shared__ float4 ov1v[128], ov2v[128];
    __shared__ float S[5], red[20];
    __shared__ float sa1[64], sa2[64], sdd[64], smu[64], srs[64];
    const int t = threadIdx.x;
    const float* ov1 = (const float*)ov1v;
    const float* ov2 = (const float*)ov2v;

    {   // stage ov rows (sum of NP partial slabs, z=1 -> slabs 4..7)
        const int tt = t & 127;
        const int row = b * 2 + (t >> 7);
        float sx = 0.f, sy = 0.f, sz = 0.f, sw = 0.f;
        #pragma unroll
        for (int pp = 0; pp < NP; ++pp) {
            const float4* q4 = (const float4*)(base + (size_t)(4 + pp) * SLAB
                                               + (size_t)row * DD);
            float4 v = q4[tt];
            sx += v.x; sy += v.y; sz += v.z; sw += v.w;
        }
        float4 s = make_float4(sx, sy, sz, sw);
        if (t < 128) ov1v[tt] = s; else ov2v[tt] = s;
    }
    __syncthreads();

    float v0a = ov1[t], v0b = ov1[t + 256], v1a = ov2[t], v1b = ov2[t + 256];
    float s[5];
    s[0] = v0a + v0b;
    s[1] = v1a + v1b;
    s[2] = v0a * v0a + v0b * v0b;
    s[3] = v0a * v1a + v0b * v1b;
    s[4] = v1a * v1a + v1b * v1b;
    #pragma unroll
    for (int off = 32; off; off >>= 1) {
        #pragma unroll
        for (int q = 0; q < 5; ++q) s[q] += __shfl_down(s[q], off);
    }
    const int lane = t & 63, wv = t >> 6;
    if (lane == 0) {
        #pragma unroll
        for (int q = 0; q < 5; ++q) red[wv * 5 + q] = s[q];
    }
    __syncthreads();
    if (t == 0) {
        #pragma unroll
        for (int q = 0; q < 5; ++q) S[q] = red[q] + red[5 + q] + red[10 + q] + red[15 + q];
    }
    __syncthreads();

    if (t < 64) {
        const float S1 = S[0], S2 = S[1], S11 = S[2], S12 = S[3], S22 = S[4];
        int i = chunk * 64 + t;
        float wp0 = wp[b * 2], wp1 = wp[b * 2 + 1];
        float iv1 = 0.f, iv2 = 0.f, dv1 = 0.f, dv2 = 0.f;
        #pragma unroll
        for (int pp = 0; pp < NP; ++pp) {
            const float* s0 = base + (size_t)(0 + pp) * SLAB;   // iv slabs 0..3
            const float* s2 = base + (size_t)(8 + pp) * SLAB;   // dv slabs 8..11
            iv1 += s0[(size_t)(b * 2 + 0) * DD + i];
            iv2 += s0[(size_t)(b * 2 + 1) * DD + i];
            dv1 += s2[(size_t)(b * 2 + 0) * DD + i];
            dv2 += s2[(size_t)(b * 2 + 1) * DD + i];
        }
        float a1 = wp0 * iv1;
        float a2 = wp1 * iv2;
        float dd = wp0 * dv1 + wp1 * dv2;
        float mu = (a1 * S1 + a2 * S2 + dd) * (1.0f / DD);
        float e2 = (a1 * a1 * S11 + 2.0f * a1 * a2 * S12 + a2 * a2 * S22
                    + 2.0f * (a1 * ov1[i] + a2 * ov2[i]) * dd + dd * dd) * (1.0f / DD);
        float var = e2 - mu * mu;
        sa1[t] = a1; sa2[t] = a2; sdd[t] = dd; smu[t] = mu;
        srs[t] = rsqrtf(var + 1e-5f);
    }
    __syncthreads();

    const int ci = t & 127, rh = t >> 7;
    const float4 o1 = ov1v[ci], o2 = ov2v[ci];   // loop-invariant, hoisted
    const int jj = ci * 4;
    float* obase = outp + ((size_t)b * DD + chunk * 64) * DD;
    #pragma unroll 2
    for (int rr = 0; rr < 32; ++rr) {
        int r = rr * 2 + rh;
        int irow = chunk * 64 + r;
        float a1 = sa1[r], a2 = sa2[r], dd = sdd[r], mu = smu[r], rs = srs[r];
        float4 w;
        w.x = a1 * o1.x + a2 * o2.x + ((irow == jj)     ? dd : 0.f);
        w.y = a1 * o1.y + a2 * o2.y + ((irow == jj + 1) ? dd : 0.f);
        w.z = a1 * o1.z + a2 * o2.z + ((irow == jj + 2) ? dd : 0.f);
        w.w = a1 * o1.w + a2 * o2.w + ((irow == jj + 3) ? dd : 0.f);
        w.x = (w.x - mu) * rs; w.y = (w.y - mu) * rs;
        w.z = (w.z - mu) * rs; w.w = (w.w - mu) * rs;
        ((float4*)(obase + (size_t)r * DD))[ci] = w;
    }
}

// ---------------------------------------------------------------- kernel D
__global__ void bias_mix(const float* __restrict__ ws_f,
                         const float* __restrict__ bp,
                         float* __restrict__ outp) {
    const float* base = ws_f + WS_F_BASE;
    int b = blockIdx.x;
    int t = threadIdx.x;
    float p0 = bp[b * 2], p1 = bp[b * 2 + 1];
    float s0a = 0.f, s0b = 0.f, s1a = 0.f, s1b = 0.f;
    #pragma unroll
    for (int pp = 0; pp < NP; ++pp) {
        const float* bv = base + (size_t)(12 + pp) * SLAB;   // bv slabs 12..15
        s0a += bv[(size_t)(b * 2 + 0) * DD + t];
        s0b += bv[(size_t)(b * 2 + 0) * DD + t + 256];
        s1a += bv[(size_t)(b * 2 + 1) * DD + t];
        s1b += bv[(size_t)(b * 2 + 1) * DD + t + 256];
    }
    outp[(size_t)b * DD + t]       = p0 * s0a + p1 * s1a;
    outp[(size_t)b * DD + t + 256] = p0 * s0b + p1 * s1b;
}

// ---------------------------------------------------------------- launch
extern "C" void kernel_launch(void* const* d_in, const int* in_sizes, int n_in,
                              void* d_out, int out_size, void* d_ws, size_t ws_size,
                              hipStream_t stream) {
    const float* x      = (const float*)d_in[0];
    const float* wprobs = (const float*)d_in[1];
    const float* bprobs = (const float*)d_in[2];
    const float* w_in   = (const float*)d_in[3];
    const float* w_out  = (const float*)d_in[4];
    const float* w_diag = (const float*)d_in[5];
    const float* w_bias = (const float*)d_in[6];
    const int*   widx   = (const int*)d_in[7];
    const int*   bidx   = (const int*)d_in[8];
    float* out = (float*)d_out;
    int*   wsI = (int*)d_ws;
    float* wsF = (float*)d_ws;

    build_lists<<<1, BK, 0, stream>>>(widx, bidx, wsI);

    expert_vm<<<dim3(4, 48, 16), 256, 0, stream>>>(x, w_in, w_out, w_diag, w_bias,
                                                   wsI, wsF);

    gen_write<<<dim3(8, BB), 256, 0, stream>>>(wsF, wprobs, out);

    bias_mix<<<BB, 256, 0, stream>>>(wsF, bprobs, out + (size_t)BB * DD * DD);
}

// Round 5
// 393.356 us; speedup vs baseline: 1.3106x; 1.0080x over previous
//
#include <hip/hip_runtime.h>
#include <math.h>

#define BB 256
#define KK 2
#define EE 16
#define DD 512
#define BK (BB*KK)   // 512
#define NP 4         // K-dim partials (i-split)

// ws layout (ints/floats over same buffer):
//   int  wlist[EE*BK]   @ int 1024
//   int  blist[EE*BK]   @ int 10240
//   int  wchunks        @ int 18432  ([0]=count, [1..] = e | r0<<8 | rows<<20)
//   int  bchunks        @ int 18560
//   f32  16 partial slabs @ f32 20480: slab(z,p) = (z*NP+p)*SLAB, each BK*DD
//        z: 0=iv 1=ov 2=dv 3=bv; p: i-range [p*128,(p+1)*128)
#define WCH 18432
#define BCH 18560
#define WS_F_BASE 20480
#define SLAB (BK*DD)

// ---------------------------------------------------------------- kernel A
__global__ void build_lists(const int* __restrict__ widx,
                            const int* __restrict__ bidx,
                            int* __restrict__ ws) {
    __shared__ int scw[16], scb[16];
    int* wlist = ws + 1024;
    int* blist = ws + 10240;
    const int t = threadIdx.x;        // 0..511
    if (t < 16) { scw[t] = 0; scb[t] = 0; }
    __syncthreads();
    int e = widx[t];
    int p = atomicAdd(&scw[e], 1);
    wlist[e * BK + p] = t;
    int eb = bidx[t];
    int pb = atomicAdd(&scb[eb], 1);
    blist[eb * BK + pb] = t;
    __syncthreads();
    if (t == 0) {
        int nc = 0;
        for (int e2 = 0; e2 < 16; ++e2) {
            int n = scw[e2];
            for (int r = 0; r < n; r += 16)
                ws[WCH + 1 + nc++] = e2 | (r << 8) | (min(16, n - r) << 20);
        }
        ws[WCH] = nc;
    }
    if (t == 64) {
        int nc = 0;
        for (int e2 = 0; e2 < 16; ++e2) {
            int n = scb[e2];
            for (int r = 0; r < n; r += 16)
                ws[BCH + 1 + nc++] = e2 | (r << 8) | (min(16, n - r) << 20);
        }
        ws[BCH] = nc;
    }
}

// ---------------------------------------------------------------- kernel B
// grid (2 colchunks, 48 chunk slots, 16 z*p), block 256.
// Chunk = expert e, up to 16 (b,k) rows; this block does K-partial
// i in [ip*128,(ip+1)*128) for 256 distinct cols. Thread: 1 col x 16 rows.
// Per i: 1 coalesced 4B load + 4 broadcast ds_read_b128 + 16 FMA.
__launch_bounds__(256)
__global__ void expert_vm(const float* __restrict__ x,
                          const float* __restrict__ w_in,
                          const float* __restrict__ w_out,
                          const float* __restrict__ w_diag,
                          const float* __restrict__ w_bias,
                          const int* __restrict__ ws_i,
                          float* __restrict__ ws_f) {
    const int zp = blockIdx.z;                 // 0..15
    const int z = zp >> 2, ip = zp & 3;
    const int* ch = ws_i + ((z < 3) ? WCH : BCH);
    const int slot = blockIdx.y;
    if (slot >= ch[0]) return;
    const int desc = ch[1 + slot];
    const int e = desc & 0xff, r0 = (desc >> 8) & 0xfff, rows = desc >> 20;
    const int* list = ws_i + ((z < 3) ? 1024 : 10240) + e * BK + r0;
    const int i0 = ip * 128;
    const float* W = (z == 0 ? w_in : z == 1 ? w_out : z == 2 ? w_diag : w_bias)
                     + (size_t)e * DD * DD + (size_t)i0 * DD;
    float* out = ws_f + WS_F_BASE + (size_t)zp * SLAB;

    __shared__ int plist[16];
    __shared__ float4 xs[128][4];      // [i_local][q]: rows 4q..4q+3 (8KB)
    const int t = threadIdx.x;
    if (t < 16) plist[t] = (t < rows) ? list[t] : -1;
    __syncthreads();
    #pragma unroll
    for (int k = 0; k < 2; ++k) {
        int idx = t + k * 256;         // 0..511
        int i = idx >> 2, q = idx & 3;
        int p0 = plist[q * 4 + 0], p1 = plist[q * 4 + 1];
        int p2 = plist[q * 4 + 2], p3 = plist[q * 4 + 3];
        float4 v;
        // plist entries are (b,k) flat 0..511; x row is p>>1.
        v.x = (p0 >= 0) ? x[(p0 >> 1) * DD + i0 + i] : 0.f;
        v.y = (p1 >= 0) ? x[(p1 >> 1) * DD + i0 + i] : 0.f;
        v.z = (p2 >= 0) ? x[(p2 >> 1) * DD + i0 + i] : 0.f;
        v.w = (p3 >= 0) ? x[(p3 >> 1) * DD + i0 + i] : 0.f;
        xs[i][q] = v;
    }
    __syncthreads();

    const int col = blockIdx.x * 256 + t;      // 256 distinct cols per block
    const float* Wc = W + col;
    float acc[16];
    #pragma unroll
    for (int r = 0; r < 16; ++r) acc[r] = 0.f;

    #pragma unroll 8
    for (int i = 0; i < 128; ++i) {
        float w = Wc[(size_t)i * DD];          // coalesced 4B/lane
        float4 xa = xs[i][0];                  // broadcast b128 reads
        float4 xb = xs[i][1];
        float4 xc = xs[i][2];
        float4 xd = xs[i][3];
        acc[0]  += xa.x * w; acc[1]  += xa.y * w; acc[2]  += xa.z * w; acc[3]  += xa.w * w;
        acc[4]  += xb.x * w; acc[5]  += xb.y * w; acc[6]  += xb.z * w; acc[7]  += xb.w * w;
        acc[8]  += xc.x * w; acc[9]  += xc.y * w; acc[10] += xc.z * w; acc[11] += xc.w * w;
        acc[12] += xd.x * w; acc[13] += xd.y * w; acc[14] += xd.z * w; acc[15] += xd.w * w;
    }
    #pragma unroll
    for (int r = 0; r < 16; ++r) {
        int p = plist[r];
        if (p >= 0) out[(size_t)p * DD + col] = acc[r];
    }
}

// ---------------------------------------------------------------- kernel C
// grid (8 chunks, 256 batch), block 256. Closed-form LayerNorm of the
// rank-2+diag mixture, folded into per-row coefficients:
//   out[i][j] = af1*ov1[j] + af2*ov2[j] + cm  (+ cc at j==i)
// where af1=a1*rs, af2=a2*rs, cm=-mu*rs, cc=dd*rs.  chunk-0 blocks also
// emit the bias mix (fused former bias_mix kernel).
__launch_bounds__(256)
__global__ void gen_write(const float* __restrict__ ws_f,
                          const float* __restrict__ wp,
                          const float* __restrict__ bp,
                          float* __restrict__ outp,
                          float* __restrict__ outb) {
    const int b = blockIdx.y;
    const int chunk = blockIdx.x;          // 64-row chunk
    const float* base = ws_f + WS_F_BASE;

    __shared__ float4 ov1v[128], ov2v[128];
    __shared__ float S[5], red[20];
    __shared__ float saf1[64], saf2[64], scm[64], scc[64];
    const int t = threadIdx.x;
    const float* ov1 = (const float*)ov1v;
    const float* ov2 = (const float*)ov2v;

    {   // stage ov rows (sum of NP partial slabs, z=1 -> slabs 4..7)
        const int tt = t & 127;
        const int row = b * 2 + (t >> 7);
        float sx = 0.f, sy = 0.f, sz = 0.f, sw = 0.f;
        #pragma unroll
        for (int pp = 0; pp < NP; ++pp) {
            const float4* q4 = (const float4*)(base + (size_t)(4 + pp) * SLAB
                                               + (size_t)row * DD);
            float4 v = q4[tt];
            sx += v.x; sy += v.y; sz += v.z; sw += v.w;
        }
        float4 s = make_float4(sx, sy, sz, sw);
        if (t < 128) ov1v[tt] = s; else ov2v[tt] = s;
    }
    __syncthreads();

    float v0a = ov1[t], v0b = ov1[t + 256], v1a = ov2[t], v1b = ov2[t + 256];
    float s[5];
    s[0] = v0a + v0b;
    s[1] = v1a + v1b;
    s[2] = v0a * v0a + v0b * v0b;
    s[3] = v0a * v1a + v0b * v1b;
    s[4] = v1a * v1a + v1b * v1b;
    #pragma unroll
    for (int off = 32; off; off >>= 1) {
        #pragma unroll
        for (int q = 0; q < 5; ++q) s[q] += __shfl_down(s[q], off);
    }
    const int lane = t & 63, wv = t >> 6;
    if (lane == 0) {
        #pragma unroll
        for (int q = 0; q < 5; ++q) red[wv * 5 + q] = s[q];
    }
    __syncthreads();
    if (t == 0) {
        #pragma unroll
        for (int q = 0; q < 5; ++q) S[q] = red[q] + red[5 + q] + red[10 + q] + red[15 + q];
    }
    __syncthreads();

    if (t < 64) {
        const float S1 = S[0], S2 = S[1], S11 = S[2], S12 = S[3], S22 = S[4];
        int i = chunk * 64 + t;
        float wp0 = wp[b * 2], wp1 = wp[b * 2 + 1];
        float iv1 = 0.f, iv2 = 0.f, dv1 = 0.f, dv2 = 0.f;
        #pragma unroll
        for (int pp = 0; pp < NP; ++pp) {
            const float* s0 = base + (size_t)(0 + pp) * SLAB;   // iv slabs 0..3
            const float* s2 = base + (size_t)(8 + pp) * SLAB;   // dv slabs 8..11
            iv1 += s0[(size_t)(b * 2 + 0) * DD + i];
            iv2 += s0[(size_t)(b * 2 + 1) * DD + i];
            dv1 += s2[(size_t)(b * 2 + 0) * DD + i];
            dv2 += s2[(size_t)(b * 2 + 1) * DD + i];
        }
        float a1 = wp0 * iv1;
        float a2 = wp1 * iv2;
        float dd = wp0 * dv1 + wp1 * dv2;
        float mu = (a1 * S1 + a2 * S2 + dd) * (1.0f / DD);
        float e2 = (a1 * a1 * S11 + 2.0f * a1 * a2 * S12 + a2 * a2 * S22
                    + 2.0f * (a1 * ov1[i] + a2 * ov2[i]) * dd + dd * dd) * (1.0f / DD);
        float var = e2 - mu * mu;
        float rs = rsqrtf(var + 1e-5f);
        saf1[t] = a1 * rs;
        saf2[t] = a2 * rs;
        scm[t]  = -mu * rs;
        scc[t]  = dd * rs;
    }
    __syncthreads();

    const int ci = t & 127, rh = t >> 7;
    const float4 o1 = ov1v[ci], o2 = ov2v[ci];   // loop-invariant, hoisted
    const int jj = ci * 4;
    float* obase = outp + ((size_t)b * DD + chunk * 64) * DD;
    #pragma unroll 2
    for (int rr = 0; rr < 32; ++rr) {
        int r = rr * 2 + rh;
        int irow = chunk * 64 + r;
        float af1 = saf1[r], af2 = saf2[r], cm = scm[r], cc = scc[r];
        float4 w;
        w.x = fmaf(af1, o1.x, fmaf(af2, o2.x, cm));
        w.y = fmaf(af1, o1.y, fmaf(af2, o2.y, cm));
        w.z = fmaf(af1, o1.z, fmaf(af2, o2.z, cm));
        w.w = fmaf(af1, o1.w, fmaf(af2, o2.w, cm));
        int d = irow - jj;
        w.x += (d == 0) ? cc : 0.f;
        w.y += (d == 1) ? cc : 0.f;
        w.z += (d == 2) ? cc : 0.f;
        w.w += (d == 3) ? cc : 0.f;
        ((float4*)(obase + (size_t)r * DD))[ci] = w;
    }

    // fused bias mix: chunk-0 blocks write outb[b][:]
    if (chunk == 0) {
        float p0 = bp[b * 2], p1 = bp[b * 2 + 1];
        float s0a = 0.f, s0b = 0.f, s1a = 0.f, s1b = 0.f;
        #pragma unroll
        for (int pp = 0; pp < NP; ++pp) {
            const float* bv = base + (size_t)(12 + pp) * SLAB;   // bv slabs 12..15
            s0a += bv[(size_t)(b * 2 + 0) * DD + t];
            s0b += bv[(size_t)(b * 2 + 0) * DD + t + 256];
            s1a += bv[(size_t)(b * 2 + 1) * DD + t];
            s1b += bv[(size_t)(b * 2 + 1) * DD + t + 256];
        }
        outb[(size_t)b * DD + t]       = p0 * s0a + p1 * s1a;
        outb[(size_t)b * DD + t + 256] = p0 * s0b + p1 * s1b;
    }
}

// ---------------------------------------------------------------- launch
extern "C" void kernel_launch(void* const* d_in, const int* in_sizes, int n_in,
                              void* d_out, int out_size, void* d_ws, size_t ws_size,
                              hipStream_t stream) {
    const float* x      = (const float*)d_in[0];
    const float* wprobs = (const float*)d_in[1];
    const float* bprobs = (const float*)d_in[2];
    const float* w_in   = (const float*)d_in[3];
    const float* w_out  = (const float*)d_in[4];
    const float* w_diag = (const float*)d_in[5];
    const float* w_bias = (const float*)d_in[6];
    const int*   widx   = (const int*)d_in[7];
    const int*   bidx   = (const int*)d_in[8];
    float* out = (float*)d_out;
    int*   wsI = (int*)d_ws;
    float* wsF = (float*)d_ws;

    build_lists<<<1, BK, 0, stream>>>(widx, bidx, wsI);

    expert_vm<<<dim3(2, 48, 16), 256, 0, stream>>>(x, w_in, w_out, w_diag, w_bias,
                                                   wsI, wsF);

    gen_write<<<dim3(8, BB), 256, 0, stream>>>(wsF, wprobs, bprobs, out,
                                               out + (size_t)BB * DD * DD);
}